// Round 5
// baseline (788.702 us; speedup 1.0000x reference)
//
#include <hip/hip_runtime.h>
#include <hip/hip_bf16.h>

// ---------------------------------------------------------------------------
// AttentionHeteroConv. R12 = R11 with:
//  (1) attn ATN 4->8: two A-row-tiles per wave share each B-fragment read ->
//      wipbf L2 traffic halves (1.2GB -> 600MB/dispatch). acc[2][6] (48 VGPR),
//      __launch_bounds__(256,6).
//  (2) launches 9 -> 6: prep fused into transform (block-role branch);
//      CSR stored as ushort (ids < 65536) so BOTH directions' csr fit in the
//      old int-csr footprint -> single fill2 launch; both attn directions in
//      ONE launch (block-range dispatch).
// hist2/scan2/outproj unchanged.
// ---------------------------------------------------------------------------

#define C 128
#define NHEAD 4
#define DH 32
#define QK_SCALE 0.17677669529663687f  // 1/sqrt(32)

typedef __attribute__((ext_vector_type(8))) short bf16x8;
typedef __attribute__((ext_vector_type(4))) short short4v;
typedef __attribute__((ext_vector_type(2))) short short2v;
typedef __attribute__((ext_vector_type(4))) float f32x4;

__device__ __forceinline__ short f2bf(float f) {
    unsigned u = __float_as_uint(f);
    unsigned r = u + 0x7FFFu + ((u >> 16) & 1u);   // round-to-nearest-even
    return (short)(r >> 16);
}

// ---------------------------------------------------------------------------
// K1: transform (+prep tail blocks). Blocks [0,TB): 64-row transform tiles.
// Blocks [TB,TB+96): wip2bf. Blocks [TB+96,...): zero curA/curB.
// ---------------------------------------------------------------------------
__global__ __launch_bounds__(256, 2) void transform_prep_kernel(
    const float* __restrict__ xu, const float* __restrict__ xi,
    int NU, int NTOT,
    const float* __restrict__ Wnb, const float* __restrict__ bnb,
    const float* __restrict__ Wself, const float* __restrict__ bself,
    float* __restrict__ h, float* __restrict__ selfout,
    const float* __restrict__ Wip, unsigned* __restrict__ img,
    int* __restrict__ curA, int nA, int* __restrict__ curB, int nB, int TB)
{
    const int tid = threadIdx.x;

    if ((int)blockIdx.x >= TB) {
        int bid2 = (int)blockIdx.x - TB;
        if (bid2 < 96) {
            // wip2bf: Wip fp32 [384][128] -> bf16 image [ks][384][32]
            int id = bid2 * 256 + tid;           // 24576 pair-slots
            int ks = id / (384 * 16);
            int rem = id - ks * (384 * 16);
            int n = rem >> 4, kk = rem & 15;
            float a = Wip[(size_t)n * C + ks * 32 + kk * 2 + 0];
            float b = Wip[(size_t)n * C + ks * 32 + kk * 2 + 1];
            unsigned pa = ((unsigned)(unsigned short)f2bf(a))
                        | (((unsigned)(unsigned short)f2bf(b)) << 16);
            img[(size_t)ks * 6144 + n * 16 + kk] = pa;
        } else {
            int i = (bid2 - 96) * 256 + tid;
            if (i < nA) curA[i] = 0;
            else if (i < nA + nB) curB[i - nA] = 0;
        }
        return;
    }

    __shared__ float As[64 * 132];   // 33792 B
    __shared__ float Bs[256 * 36];   // 36864 B
    __shared__ float biasS[256];

    const int row0 = blockIdx.x * 64;

    biasS[tid] = (tid < 128) ? bnb[tid] : bself[tid - 128];

#pragma unroll
    for (int i = 0; i < 8; i++) {
        int id = tid + i * 256;
        int r = id >> 5, c4 = id & 31;
        int row = row0 + r;
        float4 v = make_float4(0.f, 0.f, 0.f, 0.f);
        if (row < NTOT) {
            v = (row < NU) ? ((const float4*)xu)[(size_t)row * 32 + c4]
                           : ((const float4*)xi)[(size_t)(row - NU) * 32 + c4];
        }
        *(float4*)&As[r * 132 + c4 * 4] = v;
    }

    const int tm = tid >> 5;   // 0..7
    const int tn = tid & 31;   // 0..31

    float acc[8][8];
#pragma unroll
    for (int m = 0; m < 8; m++)
#pragma unroll
        for (int j = 0; j < 8; j++) acc[m][j] = 0.f;

    for (int ks = 0; ks < 4; ks++) {
        __syncthreads();
#pragma unroll
        for (int i = 0; i < 8; i++) {
            int id = tid + i * 256;          // 2048 = 256 n x 8 q
            int n = id >> 3, q = id & 7;
            const float4* src = (n < 128)
                ? &((const float4*)Wnb)[(size_t)n * 32 + ks * 8 + q]
                : &((const float4*)Wself)[(size_t)(n - 128) * 32 + ks * 8 + q];
            *(float4*)&Bs[n * 36 + q * 4] = *src;
        }
        __syncthreads();

        for (int k4 = 0; k4 < 8; k4++) {
            float4 a[8];
#pragma unroll
            for (int m = 0; m < 8; m++)
                a[m] = *(const float4*)&As[(tm * 8 + m) * 132 + ks * 32 + k4 * 4];
            float4 b[8];
#pragma unroll
            for (int j = 0; j < 8; j++)
                b[j] = *(const float4*)&Bs[(tn + 32 * j) * 36 + k4 * 4];
#pragma unroll
            for (int m = 0; m < 8; m++) {
                float4 av = a[m];
#pragma unroll
                for (int j = 0; j < 8; j++) {
                    float4 bv = b[j];
                    acc[m][j] += av.x * bv.x + av.y * bv.y
                               + av.z * bv.z + av.w * bv.w;
                }
            }
        }
    }

#pragma unroll
    for (int m = 0; m < 8; m++) {
        int row = row0 + tm * 8 + m;
        if (row < NTOT) {
#pragma unroll
            for (int j = 0; j < 8; j++) {
                int jj = tn + 32 * j;
                float v = acc[m][j] + biasS[jj];
                if (j < 4) h[(size_t)row * C + jj] = v;
                else       selfout[(size_t)row * C + (jj - 128)] = v;
            }
        }
    }
}

// ---------------------------------------------------------------------------
// Merged histogram over both edge lists.
// ---------------------------------------------------------------------------
__global__ __launch_bounds__(256) void hist2_kernel(
    const int* __restrict__ dstA, int nA, int* __restrict__ curA,
    const int* __restrict__ dstB, int nB, int* __restrict__ curB)
{
    int i = blockIdx.x * 256 + threadIdx.x;
    if (i < nA) atomicAdd(&curA[dstA[i]], 1);
    else if (i < nA + nB) atomicAdd(&curB[dstB[i - nA]], 1);
}

// ---------------------------------------------------------------------------
// Scan: 2 blocks (block 0 -> curA/nA, block 1 -> curB/nB), 1024 threads,
// 4 elems/thread.
// ---------------------------------------------------------------------------
__global__ __launch_bounds__(1024) void scan2_kernel(
    int* __restrict__ curA, int nA, int* __restrict__ curB, int nB)
{
    int* cur = (blockIdx.x == 0) ? curA : curB;
    const int n = (blockIdx.x == 0) ? nA : nB;

    __shared__ int wsum[16];
    __shared__ int carryS;
    const int tid = threadIdx.x, lane = tid & 63, wv = tid >> 6;
    if (tid == 0) carryS = 0;
    __syncthreads();
    for (int base = 0; base < n; base += 4096) {
        int i0 = base + tid * 4;
        int v0 = 0, v1 = 0, v2 = 0, v3 = 0;
        if (i0 + 3 < n) {
            int4 t = *(const int4*)&cur[i0];
            v0 = t.x; v1 = t.y; v2 = t.z; v3 = t.w;
        } else {
            if (i0 < n) v0 = cur[i0];
            if (i0 + 1 < n) v1 = cur[i0 + 1];
            if (i0 + 2 < n) v2 = cur[i0 + 2];
            if (i0 + 3 < n) v3 = cur[i0 + 3];
        }
        int s1 = v0 + v1, s2 = s1 + v2, s3 = s2 + v3;
        int x = s3;
#pragma unroll
        for (int d = 1; d < 64; d <<= 1) {
            int t = __shfl_up(x, d, 64);
            if (lane >= d) x += t;
        }
        if (lane == 63) wsum[wv] = x;
        int carry = carryS;
        __syncthreads();
        int wpre = 0;
#pragma unroll
        for (int w2 = 0; w2 < 16; w2++) wpre += (w2 < wv) ? wsum[w2] : 0;
        int excl = x - s3 + wpre + carry;
        if (i0 + 3 < n) {
            int4 st; st.x = excl; st.y = excl + v0; st.z = excl + s1; st.w = excl + s2;
            *(int4*)&cur[i0] = st;
        } else {
            if (i0 < n) cur[i0] = excl;
            if (i0 + 1 < n) cur[i0 + 1] = excl + v0;
            if (i0 + 2 < n) cur[i0 + 2] = excl + s1;
            if (i0 + 3 < n) cur[i0 + 3] = excl + s2;
        }
        __syncthreads();
        if (tid == 0) {
            int t = 0;
#pragma unroll
            for (int w2 = 0; w2 < 16; w2++) t += wsum[w2];
            carryS = carry + t;
        }
        __syncthreads();
    }
}

// ---------------------------------------------------------------------------
// Merged fill: CSR entries stored as ushort (node ids < 65536).
// ---------------------------------------------------------------------------
__global__ __launch_bounds__(256) void fill2_kernel(
    const int* __restrict__ srcA, const int* __restrict__ dstA, int nA,
    int* __restrict__ curA, unsigned short* __restrict__ csrA,
    const int* __restrict__ srcB, const int* __restrict__ dstB, int nB,
    int* __restrict__ curB, unsigned short* __restrict__ csrB)
{
    int i = blockIdx.x * 256 + threadIdx.x;
    if (i < nA) {
        int p = atomicAdd(&curA[dstA[i]], 1);
        csrA[p] = (unsigned short)srcA[i];
    } else if (i < nA + nB) {
        int j = i - nA;
        int p = atomicAdd(&curB[dstB[j]], 1);
        csrB[p] = (unsigned short)srcB[j];
    }
}

// ---------------------------------------------------------------------------
// K4: fused gather-aggregate + bf16-MFMA qkv + in-register attention.
// BOTH directions in one launch: blocks [0,nbB) = dir B, rest = dir A.
// ATN=8: 8 nodes/block, A tile [32][136] bf16, two 16-row A-tiles share each
// B-fragment (halves wipbf traffic). acc[2][6] f32x4.
// ---------------------------------------------------------------------------
#define ATN 8

__global__ __launch_bounds__(256, 6) void attn2_kernel(
    const float* __restrict__ hB, const unsigned short* __restrict__ csrB,
    const int* __restrict__ curB, const float* __restrict__ selfB,
    float* __restrict__ omB, int nNodesB, int nbB,
    const float* __restrict__ hA, const unsigned short* __restrict__ csrA,
    const int* __restrict__ curA, const float* __restrict__ selfA,
    float* __restrict__ omA, int nNodesA,
    const short* __restrict__ wipbf, const float* __restrict__ bip)
{
    __shared__ char Ash[32 * 272];   // bf16 A tile [32 rows][136 bf16]
    __shared__ float cinv[ATN];

    const int tid = threadIdx.x;
    const int lane = tid & 63;
    const int wv = tid >> 6;

    const int bid = (int)blockIdx.x;
    const bool dirB = bid < nbB;
    const float* h_src = dirB ? hB : hA;
    const unsigned short* csr = dirB ? csrB : csrA;
    const int* cur = dirB ? curB : curA;
    const float* selfF = dirB ? selfB : selfA;
    float* omean_g = dirB ? omB : omA;
    const int n_nodes = dirB ? nNodesB : nNodesA;
    const int node0 = (dirB ? bid : bid - nbB) * ATN;

    // ---- P0a: self rows (A row nodeLocal*4+0, bf16). 8 nodes x 32 cols. ----
    {
        int r = tid >> 5, c4 = tid & 31;
        int node = node0 + r;
        float4 v = make_float4(0.f, 0.f, 0.f, 0.f);
        if (node < n_nodes) v = ((const float4*)selfF)[(size_t)node * 32 + c4];
        short4v b;
        b.x = f2bf(v.x); b.y = f2bf(v.y); b.z = f2bf(v.z); b.w = f2bf(v.w);
        *(short4v*)(Ash + (r * 4) * 272 + c4 * 8) = b;
    }

    // ---- P0b: gather max/min/sum; each wave aggregates TWO nodes ----
    const float2* h2 = (const float2*)h_src;
#pragma unroll
    for (int half = 0; half < 2; half++) {
        int nl = wv * 2 + half;
        int node = node0 + nl;
        float2 vs = make_float2(0.f, 0.f);
        float2 vmx = make_float2(-3.4e38f, -3.4e38f);
        float2 vmn = make_float2(3.4e38f, 3.4e38f);
        int deg = 0;
        if (node < n_nodes) {
            int start = (node == 0) ? 0 : cur[node - 1];
            int end = cur[node];
            deg = end - start;
            int e = start;
            for (; e + 8 <= end; e += 8) {
                float2 v[8];
#pragma unroll
                for (int i = 0; i < 8; i++) {
                    int s = csr[e + i];
                    v[i] = h2[(size_t)s * 64 + lane];
                }
#pragma unroll
                for (int i = 0; i < 8; i++) {
                    vs.x += v[i].x; vs.y += v[i].y;
                    vmx.x = fmaxf(vmx.x, v[i].x); vmx.y = fmaxf(vmx.y, v[i].y);
                    vmn.x = fminf(vmn.x, v[i].x); vmn.y = fminf(vmn.y, v[i].y);
                }
            }
            if (e < end) {   // masked full-width tail
                int last = end - 1;
                float2 v[8];
#pragma unroll
                for (int i = 0; i < 8; i++) {
                    int idx = e + i;
                    int s = csr[(idx <= last) ? idx : last];
                    v[i] = h2[(size_t)s * 64 + lane];
                }
#pragma unroll
                for (int i = 0; i < 8; i++) {
                    if (e + i <= last) {   // wave-uniform
                        vs.x += v[i].x; vs.y += v[i].y;
                        vmx.x = fmaxf(vmx.x, v[i].x); vmx.y = fmaxf(vmx.y, v[i].y);
                        vmn.x = fminf(vmn.x, v[i].x); vmn.y = fminf(vmn.y, v[i].y);
                    }
                }
            }
        }
        if (deg == 0) {
            vmx = make_float2(0.f, 0.f);
            vmn = make_float2(0.f, 0.f);
        }
        short2v p;
        p.x = f2bf(vmx.x); p.y = f2bf(vmx.y);
        *(short2v*)(Ash + (nl * 4 + 1) * 272 + lane * 4) = p;
        p.x = f2bf(vmn.x); p.y = f2bf(vmn.y);
        *(short2v*)(Ash + (nl * 4 + 2) * 272 + lane * 4) = p;
        p.x = f2bf(vs.x); p.y = f2bf(vs.y);
        *(short2v*)(Ash + (nl * 4 + 3) * 272 + lane * 4) = p;
        if (lane == 0) cinv[nl] = 1.f / (float)max(deg, 1);
    }
    __syncthreads();   // the ONLY barrier

    // ---- P1: MFMA qkv for head wv; two A-tiles (nodes 0-3, 4-7) share B ----
    const int quad = lane >> 4;      // node-within-tile
    const int col16 = lane & 15;     // head-dim coordinate (cols c and c+16)

    f32x4 acc[2][6];
#pragma unroll
    for (int m = 0; m < 2; m++)
#pragma unroll
        for (int t = 0; t < 6; t++) acc[m][t] = (f32x4){0.f, 0.f, 0.f, 0.f};

#pragma unroll
    for (int ks = 0; ks < 4; ks++) {
        bf16x8 af0 = *(const bf16x8*)(Ash + col16 * 272 + ks * 64 + quad * 16);
        bf16x8 af1 = *(const bf16x8*)(Ash + (16 + col16) * 272 + ks * 64 + quad * 16);
#pragma unroll
        for (int t = 0; t < 6; t++) {
            int nb = wv * 32 + (t & 1) * 16 + (t >> 1) * 128 + col16;
            bf16x8 bfr = *(const bf16x8*)((const char*)wipbf
                          + (size_t)ks * 24576 + (size_t)nb * 64 + quad * 16);
            acc[0][t] = __builtin_amdgcn_mfma_f32_16x16x32_bf16(af0, bfr, acc[0][t], 0, 0, 0);
            acc[1][t] = __builtin_amdgcn_mfma_f32_16x16x32_bf16(af1, bfr, acc[1][t], 0, 0, 0);
        }
    }

    // ---- P2: in-register attention, head wv, nodes m*4+quad (m=0,1) ----
    const float bq0 = bip[wv * 32 + col16];
    const float bq1 = bip[wv * 32 + 16 + col16];
    const float bk0 = bip[128 + wv * 32 + col16];
    const float bk1 = bip[128 + wv * 32 + 16 + col16];
    const float bv0 = bip[256 + wv * 32 + col16];
    const float bv1 = bip[256 + wv * 32 + 16 + col16];
    const float bq0s = bq0 * QK_SCALE;
    const float bq1s = bq1 * QK_SCALE;

#pragma unroll
    for (int m = 0; m < 2; m++) {
        const float ci = cinv[m * 4 + quad];
        const float cis = ci * QK_SCALE;

        float k0[5], k1[5];
#pragma unroll
        for (int s = 0; s < 4; s++) {
            k0[s] = acc[m][2][s] + bk0;
            k1[s] = acc[m][3][s] + bk1;
        }
        k0[4] = fmaf(acc[m][2][3], ci, bk0);
        k1[4] = fmaf(acc[m][3][3], ci, bk1);

        float wj[5] = {0.f, 0.f, 0.f, 0.f, 0.f};
#pragma unroll
        for (int i = 0; i < 5; i++) {
            float qi0 = (i < 4) ? fmaf(acc[m][0][i], QK_SCALE, bq0s)
                                : fmaf(acc[m][0][3], cis, bq0s);
            float qi1 = (i < 4) ? fmaf(acc[m][1][i], QK_SCALE, bq1s)
                                : fmaf(acc[m][1][3], cis, bq1s);
            float sv[5];
#pragma unroll
            for (int j = 0; j < 5; j++) sv[j] = qi0 * k0[j] + qi1 * k1[j];
#pragma unroll
            for (int j = 0; j < 5; j++) {
                sv[j] += __shfl_xor(sv[j], 1, 16);
                sv[j] += __shfl_xor(sv[j], 2, 16);
                sv[j] += __shfl_xor(sv[j], 4, 16);
                sv[j] += __shfl_xor(sv[j], 8, 16);
            }
            float mx = sv[0];
#pragma unroll
            for (int j = 1; j < 5; j++) mx = fmaxf(mx, sv[j]);
            float e[5], l = 0.f;
#pragma unroll
            for (int j = 0; j < 5; j++) { e[j] = __expf(sv[j] - mx); l += e[j]; }
            float inv = 0.2f / l;   // fold token-mean
#pragma unroll
            for (int j = 0; j < 5; j++) wj[j] = fmaf(e[j], inv, wj[j]);
        }

        float o0 = 0.f, o1 = 0.f;
#pragma unroll
        for (int j = 0; j < 5; j++) {
            float v0 = (j < 4) ? (acc[m][4][j] + bv0) : fmaf(acc[m][4][3], ci, bv0);
            float v1 = (j < 4) ? (acc[m][5][j] + bv1) : fmaf(acc[m][5][3], ci, bv1);
            o0 = fmaf(wj[j], v0, o0);
            o1 = fmaf(wj[j], v1, o1);
        }

        int node = node0 + m * 4 + quad;
        if (node < n_nodes) {
            omean_g[(size_t)node * C + wv * 32 + col16] = o0;
            omean_g[(size_t)node * C + wv * 32 + 16 + col16] = o1;
        }
    }
}

// ---------------------------------------------------------------------------
// K5: out = self(d_out) + omean @ Wop^T + bop. 64-row blocks, 8x4 tiles.
// ---------------------------------------------------------------------------
__global__ __launch_bounds__(256, 3) void outproj_kernel(
    const float* __restrict__ omean_g, const float* __restrict__ Wop,
    const float* __restrict__ bop, float* __restrict__ out, int M)
{
    __shared__ float As[64 * 132];   // 33792 B
    __shared__ float Bs[128 * 36];   // 18432 B
    __shared__ float bopS[C];

    const int tid = threadIdx.x;
    const int m0 = blockIdx.x * 64;

    if (tid < C) bopS[tid] = bop[tid];

#pragma unroll
    for (int i = 0; i < 8; i++) {
        int id = tid + i * 256;
        int r = id >> 5, c4 = id & 31;
        float4 v = make_float4(0.f, 0.f, 0.f, 0.f);
        if (m0 + r < M) v = ((const float4*)omean_g)[(size_t)(m0 + r) * 32 + c4];
        *(float4*)&As[r * 132 + c4 * 4] = v;
    }

    const int tn = tid & 31;
    const int tm = tid >> 5;
    float acc[8][4];
#pragma unroll
    for (int m = 0; m < 8; m++)
#pragma unroll
        for (int j = 0; j < 4; j++) acc[m][j] = 0.f;

    for (int ks = 0; ks < 4; ks++) {
        __syncthreads();
#pragma unroll
        for (int i = 0; i < 4; i++) {
            int id = tid + i * 256;          // 1024 = 128 n x 8 q
            int n = id >> 3, q = id & 7;
            float4 w = ((const float4*)Wop)[(size_t)n * 32 + ks * 8 + q];
            *(float4*)&Bs[n * 36 + q * 4] = w;
        }
        __syncthreads();

        for (int k4 = 0; k4 < 8; k4++) {
            float4 a[8];
#pragma unroll
            for (int m = 0; m < 8; m++)
                a[m] = *(const float4*)&As[(tm * 8 + m) * 132 + ks * 32 + k4 * 4];
            float4 b[4];
#pragma unroll
            for (int j = 0; j < 4; j++)
                b[j] = *(const float4*)&Bs[(tn + 32 * j) * 36 + k4 * 4];
#pragma unroll
            for (int m = 0; m < 8; m++) {
                float4 av = a[m];
#pragma unroll
                for (int j = 0; j < 4; j++) {
                    float4 bv = b[j];
                    acc[m][j] += av.x * bv.x + av.y * bv.y
                               + av.z * bv.z + av.w * bv.w;
                }
            }
        }
    }

#pragma unroll
    for (int m = 0; m < 8; m++) {
        int row = m0 + tm * 8 + m;
        if (row < M) {
#pragma unroll
            for (int j = 0; j < 4; j++) {
                int col = tn + 32 * j;
                float* o = &out[(size_t)row * C + col];
                *o += acc[m][j] + bopS[col];
            }
        }
    }
}

// ---------------------------------------------------------------------------
extern "C" void kernel_launch(void* const* d_in, const int* in_sizes, int n_in,
                              void* d_out, int out_size, void* d_ws, size_t ws_size,
                              hipStream_t stream) {
    const float* x_user = (const float*)d_in[0];
    const float* x_item = (const float*)d_in[1];
    const int*   ei_u2i = (const int*)d_in[2];
    const int*   ei_i2u = (const int*)d_in[3];
    const float* W_nb   = (const float*)d_in[4];
    const float* b_nb   = (const float*)d_in[5];
    const float* W_self = (const float*)d_in[6];
    const float* b_self = (const float*)d_in[7];
    const float* Wip    = (const float*)d_in[8];
    const float* bip    = (const float*)d_in[9];
    const float* Wop    = (const float*)d_in[10];
    const float* bop    = (const float*)d_in[11];

    const int NU = in_sizes[0] / C;
    const int NI = in_sizes[1] / C;
    const int E1 = in_sizes[2] / 2;
    const int E2 = in_sizes[3] / 2;
    const int NTOT = NU + NI;

    float* out_user = (float*)d_out;
    float* out_item = out_user + (size_t)NU * C;

    // workspace: wipbf (24576 floats) | h (rc) | omean (rc)
    //          | curA (NI ints) | curB (NU ints) | csrA16 (E1) | csrB16 (E2)
    float* ws = (float*)d_ws;
    short* wipbf     = (short*)ws;
    float* h_all     = ws + 24576;
    const size_t rc = (size_t)NTOT * C;
    float* omean_all = h_all + rc;
    int*   curA      = (int*)(omean_all + rc);     // item-side degrees (NI)
    int*   curB      = curA + NI;                  // user-side degrees (NU)
    unsigned short* csrA16 = (unsigned short*)(curB + NU);
    unsigned short* csrB16 = csrA16 + E1;

    float* h_user = h_all;
    float* h_item = h_all + (size_t)NU * C;
    float* om_user = omean_all;
    float* om_item = omean_all + (size_t)NU * C;

    // K1: transform + prep (wip2bf + zero cur arrays)
    const int TB = (NTOT + 63) / 64;
    const int PB = 96 + (NTOT + 255) / 256;
    transform_prep_kernel<<<TB + PB, 256, 0, stream>>>(
        x_user, x_item, NU, NTOT, W_nb, b_nb, W_self, b_self,
        h_all, (float*)d_out, Wip, (unsigned*)wipbf, curA, NI, curB, NU, TB);

    // K2: merged histogram
    hist2_kernel<<<(E1 + E2 + 255) / 256, 256, 0, stream>>>(
        ei_u2i + E1, E1, curA, ei_i2u + E2, E2, curB);

    // K3: both scans in one launch
    scan2_kernel<<<2, 1024, 0, stream>>>(curA, NI, curB, NU);

    // K4: merged fill (ushort CSR)
    fill2_kernel<<<(E1 + E2 + 255) / 256, 256, 0, stream>>>(
        ei_u2i, ei_u2i + E1, E1, curA, csrA16,
        ei_i2u, ei_i2u + E2, E2, curB, csrB16);

    // K5: both attention directions in one launch
    const int nbB = (NU + ATN - 1) / ATN;
    const int nbA = (NI + ATN - 1) / ATN;
    attn2_kernel<<<nbB + nbA, 256, 0, stream>>>(
        h_item, csrB16, curB, out_user, om_user, NU, nbB,
        h_user, csrA16, curA, out_item, om_item, NI,
        wipbf, bip);

    // K6: output projection
    outproj_kernel<<<(NTOT + 63) / 64, 256, 0, stream>>>(
        omean_all, Wop, bop, (float*)d_out, NTOT);
}

// Round 6
// 706.849 us; speedup vs baseline: 1.1158x; 1.1158x over previous
//
#include <hip/hip_runtime.h>
#include <hip/hip_bf16.h>

// ---------------------------------------------------------------------------
// AttentionHeteroConv. R13 = R11-attn + R12's safe launch merges.
// R12 lesson (counters): merging both gather directions into ONE dispatch
// tripled HBM traffic (FETCH 380->670MB, WRITE 75->637MB) -- two concurrent
// independent random-row streams defeat L3 reuse. attn reverted to per-
// direction dispatches, ATN=4, 8 blocks/CU (R11-proven, 135us each).
// Kept from R12 (traffic-neutral): prep fused into transform, merged hist2,
// 2-block scan2, merged fill2 with ushort CSR (ids < 65536).
// 7 launches total.
// ---------------------------------------------------------------------------

#define C 128
#define NHEAD 4
#define DH 32
#define QK_SCALE 0.17677669529663687f  // 1/sqrt(32)

typedef __attribute__((ext_vector_type(8))) short bf16x8;
typedef __attribute__((ext_vector_type(4))) short short4v;
typedef __attribute__((ext_vector_type(2))) short short2v;
typedef __attribute__((ext_vector_type(4))) float f32x4;

__device__ __forceinline__ short f2bf(float f) {
    unsigned u = __float_as_uint(f);
    unsigned r = u + 0x7FFFu + ((u >> 16) & 1u);   // round-to-nearest-even
    return (short)(r >> 16);
}

// ---------------------------------------------------------------------------
// K1: transform (+prep tail blocks). Blocks [0,TB): 64-row transform tiles.
// Blocks [TB,TB+96): wip2bf. Blocks [TB+96,...): zero curA/curB.
// ---------------------------------------------------------------------------
__global__ __launch_bounds__(256, 2) void transform_prep_kernel(
    const float* __restrict__ xu, const float* __restrict__ xi,
    int NU, int NTOT,
    const float* __restrict__ Wnb, const float* __restrict__ bnb,
    const float* __restrict__ Wself, const float* __restrict__ bself,
    float* __restrict__ h, float* __restrict__ selfout,
    const float* __restrict__ Wip, unsigned* __restrict__ img,
    int* __restrict__ curA, int nA, int* __restrict__ curB, int nB, int TB)
{
    const int tid = threadIdx.x;

    if ((int)blockIdx.x >= TB) {
        int bid2 = (int)blockIdx.x - TB;
        if (bid2 < 96) {
            // wip2bf: Wip fp32 [384][128] -> bf16 image [ks][384][32]
            int id = bid2 * 256 + tid;           // 24576 pair-slots
            int ks = id / (384 * 16);
            int rem = id - ks * (384 * 16);
            int n = rem >> 4, kk = rem & 15;
            float a = Wip[(size_t)n * C + ks * 32 + kk * 2 + 0];
            float b = Wip[(size_t)n * C + ks * 32 + kk * 2 + 1];
            unsigned pa = ((unsigned)(unsigned short)f2bf(a))
                        | (((unsigned)(unsigned short)f2bf(b)) << 16);
            img[(size_t)ks * 6144 + n * 16 + kk] = pa;
        } else {
            int i = (bid2 - 96) * 256 + tid;
            if (i < nA) curA[i] = 0;
            else if (i < nA + nB) curB[i - nA] = 0;
        }
        return;
    }

    __shared__ float As[64 * 132];   // 33792 B
    __shared__ float Bs[256 * 36];   // 36864 B
    __shared__ float biasS[256];

    const int row0 = blockIdx.x * 64;

    biasS[tid] = (tid < 128) ? bnb[tid] : bself[tid - 128];

#pragma unroll
    for (int i = 0; i < 8; i++) {
        int id = tid + i * 256;
        int r = id >> 5, c4 = id & 31;
        int row = row0 + r;
        float4 v = make_float4(0.f, 0.f, 0.f, 0.f);
        if (row < NTOT) {
            v = (row < NU) ? ((const float4*)xu)[(size_t)row * 32 + c4]
                           : ((const float4*)xi)[(size_t)(row - NU) * 32 + c4];
        }
        *(float4*)&As[r * 132 + c4 * 4] = v;
    }

    const int tm = tid >> 5;   // 0..7
    const int tn = tid & 31;   // 0..31

    float acc[8][8];
#pragma unroll
    for (int m = 0; m < 8; m++)
#pragma unroll
        for (int j = 0; j < 8; j++) acc[m][j] = 0.f;

    for (int ks = 0; ks < 4; ks++) {
        __syncthreads();
#pragma unroll
        for (int i = 0; i < 8; i++) {
            int id = tid + i * 256;          // 2048 = 256 n x 8 q
            int n = id >> 3, q = id & 7;
            const float4* src = (n < 128)
                ? &((const float4*)Wnb)[(size_t)n * 32 + ks * 8 + q]
                : &((const float4*)Wself)[(size_t)(n - 128) * 32 + ks * 8 + q];
            *(float4*)&Bs[n * 36 + q * 4] = *src;
        }
        __syncthreads();

        for (int k4 = 0; k4 < 8; k4++) {
            float4 a[8];
#pragma unroll
            for (int m = 0; m < 8; m++)
                a[m] = *(const float4*)&As[(tm * 8 + m) * 132 + ks * 32 + k4 * 4];
            float4 b[8];
#pragma unroll
            for (int j = 0; j < 8; j++)
                b[j] = *(const float4*)&Bs[(tn + 32 * j) * 36 + k4 * 4];
#pragma unroll
            for (int m = 0; m < 8; m++) {
                float4 av = a[m];
#pragma unroll
                for (int j = 0; j < 8; j++) {
                    float4 bv = b[j];
                    acc[m][j] += av.x * bv.x + av.y * bv.y
                               + av.z * bv.z + av.w * bv.w;
                }
            }
        }
    }

#pragma unroll
    for (int m = 0; m < 8; m++) {
        int row = row0 + tm * 8 + m;
        if (row < NTOT) {
#pragma unroll
            for (int j = 0; j < 8; j++) {
                int jj = tn + 32 * j;
                float v = acc[m][j] + biasS[jj];
                if (j < 4) h[(size_t)row * C + jj] = v;
                else       selfout[(size_t)row * C + (jj - 128)] = v;
            }
        }
    }
}

// ---------------------------------------------------------------------------
// Merged histogram over both edge lists.
// ---------------------------------------------------------------------------
__global__ __launch_bounds__(256) void hist2_kernel(
    const int* __restrict__ dstA, int nA, int* __restrict__ curA,
    const int* __restrict__ dstB, int nB, int* __restrict__ curB)
{
    int i = blockIdx.x * 256 + threadIdx.x;
    if (i < nA) atomicAdd(&curA[dstA[i]], 1);
    else if (i < nA + nB) atomicAdd(&curB[dstB[i - nA]], 1);
}

// ---------------------------------------------------------------------------
// Scan: 2 blocks (block 0 -> curA/nA, block 1 -> curB/nB), 1024 threads,
// 4 elems/thread.
// ---------------------------------------------------------------------------
__global__ __launch_bounds__(1024) void scan2_kernel(
    int* __restrict__ curA, int nA, int* __restrict__ curB, int nB)
{
    int* cur = (blockIdx.x == 0) ? curA : curB;
    const int n = (blockIdx.x == 0) ? nA : nB;

    __shared__ int wsum[16];
    __shared__ int carryS;
    const int tid = threadIdx.x, lane = tid & 63, wv = tid >> 6;
    if (tid == 0) carryS = 0;
    __syncthreads();
    for (int base = 0; base < n; base += 4096) {
        int i0 = base + tid * 4;
        int v0 = 0, v1 = 0, v2 = 0, v3 = 0;
        if (i0 + 3 < n) {
            int4 t = *(const int4*)&cur[i0];
            v0 = t.x; v1 = t.y; v2 = t.z; v3 = t.w;
        } else {
            if (i0 < n) v0 = cur[i0];
            if (i0 + 1 < n) v1 = cur[i0 + 1];
            if (i0 + 2 < n) v2 = cur[i0 + 2];
            if (i0 + 3 < n) v3 = cur[i0 + 3];
        }
        int s1 = v0 + v1, s2 = s1 + v2, s3 = s2 + v3;
        int x = s3;
#pragma unroll
        for (int d = 1; d < 64; d <<= 1) {
            int t = __shfl_up(x, d, 64);
            if (lane >= d) x += t;
        }
        if (lane == 63) wsum[wv] = x;
        int carry = carryS;
        __syncthreads();
        int wpre = 0;
#pragma unroll
        for (int w2 = 0; w2 < 16; w2++) wpre += (w2 < wv) ? wsum[w2] : 0;
        int excl = x - s3 + wpre + carry;
        if (i0 + 3 < n) {
            int4 st; st.x = excl; st.y = excl + v0; st.z = excl + s1; st.w = excl + s2;
            *(int4*)&cur[i0] = st;
        } else {
            if (i0 < n) cur[i0] = excl;
            if (i0 + 1 < n) cur[i0 + 1] = excl + v0;
            if (i0 + 2 < n) cur[i0 + 2] = excl + s1;
            if (i0 + 3 < n) cur[i0 + 3] = excl + s2;
        }
        __syncthreads();
        if (tid == 0) {
            int t = 0;
#pragma unroll
            for (int w2 = 0; w2 < 16; w2++) t += wsum[w2];
            carryS = carry + t;
        }
        __syncthreads();
    }
}

// ---------------------------------------------------------------------------
// Merged fill: CSR entries stored as ushort (node ids < 65536).
// ---------------------------------------------------------------------------
__global__ __launch_bounds__(256) void fill2_kernel(
    const int* __restrict__ srcA, const int* __restrict__ dstA, int nA,
    int* __restrict__ curA, unsigned short* __restrict__ csrA,
    const int* __restrict__ srcB, const int* __restrict__ dstB, int nB,
    int* __restrict__ curB, unsigned short* __restrict__ csrB)
{
    int i = blockIdx.x * 256 + threadIdx.x;
    if (i < nA) {
        int p = atomicAdd(&curA[dstA[i]], 1);
        csrA[p] = (unsigned short)srcA[i];
    } else if (i < nA + nB) {
        int j = i - nA;
        int p = atomicAdd(&curB[dstB[j]], 1);
        csrB[p] = (unsigned short)srcB[j];
    }
}

// ---------------------------------------------------------------------------
// K4: fused gather-aggregate + bf16-MFMA qkv + in-register attention.
// R11-proven: 4 nodes/block, one direction per dispatch (keeps the gather
// stream L3-resident), 8 blocks/CU. ushort CSR.
// ---------------------------------------------------------------------------
#define ATN 4

__global__ __launch_bounds__(256, 8) void attn_fused_kernel(
    const float* __restrict__ h_src, const unsigned short* __restrict__ csr,
    const int* __restrict__ cur, const float* __restrict__ selfF,
    const short* __restrict__ wipbf, const float* __restrict__ bip,
    float* __restrict__ omean_g, int n_nodes)
{
    __shared__ char Ash[16 * 272];   // bf16 A tile [16 rows][136 bf16]
    __shared__ float cinv[ATN];

    const int tid = threadIdx.x;
    const int lane = tid & 63;
    const int wv = tid >> 6;
    const int node0 = blockIdx.x * ATN;

    // ---- P0a: self rows (A row node*4+0, bf16) ----
    if (tid < 128) {
        int r = tid >> 5, c4 = tid & 31;
        int node = node0 + r;
        float4 v = make_float4(0.f, 0.f, 0.f, 0.f);
        if (node < n_nodes) v = ((const float4*)selfF)[(size_t)node * 32 + c4];
        short4v b;
        b.x = f2bf(v.x); b.y = f2bf(v.y); b.z = f2bf(v.z); b.w = f2bf(v.w);
        *(short4v*)(Ash + (r * 4) * 272 + c4 * 8) = b;
    }

    // ---- P0b: gather max/min/sum -> A rows wv*4+{1,2,3} (one node/wave) ----
    {
        const float2* h2 = (const float2*)h_src;
        int node = node0 + wv;
        float2 vs = make_float2(0.f, 0.f);
        float2 vmx = make_float2(-3.4e38f, -3.4e38f);
        float2 vmn = make_float2(3.4e38f, 3.4e38f);
        int deg = 0;
        if (node < n_nodes) {
            int start = (node == 0) ? 0 : cur[node - 1];
            int end = cur[node];
            deg = end - start;
            int e = start;
            for (; e + 8 <= end; e += 8) {
                float2 v[8];
#pragma unroll
                for (int i = 0; i < 8; i++) {
                    int s = csr[e + i];
                    v[i] = h2[(size_t)s * 64 + lane];
                }
#pragma unroll
                for (int i = 0; i < 8; i++) {
                    vs.x += v[i].x; vs.y += v[i].y;
                    vmx.x = fmaxf(vmx.x, v[i].x); vmx.y = fmaxf(vmx.y, v[i].y);
                    vmn.x = fminf(vmn.x, v[i].x); vmn.y = fminf(vmn.y, v[i].y);
                }
            }
            if (e < end) {   // masked full-width tail: one latency round
                int last = end - 1;
                float2 v[8];
#pragma unroll
                for (int i = 0; i < 8; i++) {
                    int idx = e + i;
                    int s = csr[(idx <= last) ? idx : last];
                    v[i] = h2[(size_t)s * 64 + lane];
                }
#pragma unroll
                for (int i = 0; i < 8; i++) {
                    if (e + i <= last) {   // wave-uniform
                        vs.x += v[i].x; vs.y += v[i].y;
                        vmx.x = fmaxf(vmx.x, v[i].x); vmx.y = fmaxf(vmx.y, v[i].y);
                        vmn.x = fminf(vmn.x, v[i].x); vmn.y = fminf(vmn.y, v[i].y);
                    }
                }
            }
        }
        if (deg == 0) {
            vmx = make_float2(0.f, 0.f);
            vmn = make_float2(0.f, 0.f);
        }
        short2v p;
        p.x = f2bf(vmx.x); p.y = f2bf(vmx.y);
        *(short2v*)(Ash + (wv * 4 + 1) * 272 + lane * 4) = p;
        p.x = f2bf(vmn.x); p.y = f2bf(vmn.y);
        *(short2v*)(Ash + (wv * 4 + 2) * 272 + lane * 4) = p;
        p.x = f2bf(vs.x); p.y = f2bf(vs.y);
        *(short2v*)(Ash + (wv * 4 + 3) * 272 + lane * 4) = p;
        if (lane == 0) cinv[wv] = 1.f / (float)max(deg, 1);
    }
    __syncthreads();   // the ONLY barrier

    // ---- P1: MFMA qkv for head wv only (M=16, N=6x16 tiles, K=128) ----
    const int quad = lane >> 4;      // node within block
    const int col16 = lane & 15;     // head-dim coordinate (cols c and c+16)

    f32x4 acc[6];
#pragma unroll
    for (int t = 0; t < 6; t++) acc[t] = (f32x4){0.f, 0.f, 0.f, 0.f};

#pragma unroll
    for (int ks = 0; ks < 4; ks++) {
        bf16x8 af = *(const bf16x8*)(Ash + col16 * 272 + ks * 64 + quad * 16);
#pragma unroll
        for (int t = 0; t < 6; t++) {
            int nb = wv * 32 + (t & 1) * 16 + (t >> 1) * 128 + col16;
            bf16x8 bfr = *(const bf16x8*)((const char*)wipbf
                          + (size_t)ks * 24576 + (size_t)nb * 64 + quad * 16);
            acc[t] = __builtin_amdgcn_mfma_f32_16x16x32_bf16(af, bfr, acc[t], 0, 0, 0);
        }
    }

    // ---- P2: in-register attention for head wv, node quad ----
    const float ci = cinv[quad];
    const float cis = ci * QK_SCALE;

    const float bq0 = bip[wv * 32 + col16];
    const float bq1 = bip[wv * 32 + 16 + col16];
    const float bk0 = bip[128 + wv * 32 + col16];
    const float bk1 = bip[128 + wv * 32 + 16 + col16];
    const float bv0 = bip[256 + wv * 32 + col16];
    const float bv1 = bip[256 + wv * 32 + 16 + col16];
    const float bq0s = bq0 * QK_SCALE;
    const float bq1s = bq1 * QK_SCALE;

    float k0[5], k1[5];
#pragma unroll
    for (int s = 0; s < 4; s++) { k0[s] = acc[2][s] + bk0; k1[s] = acc[3][s] + bk1; }
    k0[4] = fmaf(acc[2][3], ci, bk0);
    k1[4] = fmaf(acc[3][3], ci, bk1);

    float wj[5] = {0.f, 0.f, 0.f, 0.f, 0.f};
#pragma unroll
    for (int i = 0; i < 5; i++) {
        float qi0 = (i < 4) ? fmaf(acc[0][i], QK_SCALE, bq0s)
                            : fmaf(acc[0][3], cis, bq0s);
        float qi1 = (i < 4) ? fmaf(acc[1][i], QK_SCALE, bq1s)
                            : fmaf(acc[1][3], cis, bq1s);
        float sv[5];
#pragma unroll
        for (int j = 0; j < 5; j++) sv[j] = qi0 * k0[j] + qi1 * k1[j];
#pragma unroll
        for (int j = 0; j < 5; j++) {
            sv[j] += __shfl_xor(sv[j], 1, 16);
            sv[j] += __shfl_xor(sv[j], 2, 16);
            sv[j] += __shfl_xor(sv[j], 4, 16);
            sv[j] += __shfl_xor(sv[j], 8, 16);
        }
        float m = sv[0];
#pragma unroll
        for (int j = 1; j < 5; j++) m = fmaxf(m, sv[j]);
        float e[5], l = 0.f;
#pragma unroll
        for (int j = 0; j < 5; j++) { e[j] = __expf(sv[j] - m); l += e[j]; }
        float inv = 0.2f / l;   // fold token-mean
#pragma unroll
        for (int j = 0; j < 5; j++) wj[j] = fmaf(e[j], inv, wj[j]);
    }

    float o0 = 0.f, o1 = 0.f;
#pragma unroll
    for (int j = 0; j < 5; j++) {
        float v0 = (j < 4) ? (acc[4][j] + bv0) : fmaf(acc[4][3], ci, bv0);
        float v1 = (j < 4) ? (acc[5][j] + bv1) : fmaf(acc[5][3], ci, bv1);
        o0 = fmaf(wj[j], v0, o0);
        o1 = fmaf(wj[j], v1, o1);
    }

    int node = node0 + quad;
    if (node < n_nodes) {
        omean_g[(size_t)node * C + wv * 32 + col16] = o0;
        omean_g[(size_t)node * C + wv * 32 + 16 + col16] = o1;
    }
}

// ---------------------------------------------------------------------------
// K5: out = self(d_out) + omean @ Wop^T + bop. 64-row blocks, 8x4 tiles.
// ---------------------------------------------------------------------------
__global__ __launch_bounds__(256, 3) void outproj_kernel(
    const float* __restrict__ omean_g, const float* __restrict__ Wop,
    const float* __restrict__ bop, float* __restrict__ out, int M)
{
    __shared__ float As[64 * 132];   // 33792 B
    __shared__ float Bs[128 * 36];   // 18432 B
    __shared__ float bopS[C];

    const int tid = threadIdx.x;
    const int m0 = blockIdx.x * 64;

    if (tid < C) bopS[tid] = bop[tid];

#pragma unroll
    for (int i = 0; i < 8; i++) {
        int id = tid + i * 256;
        int r = id >> 5, c4 = id & 31;
        float4 v = make_float4(0.f, 0.f, 0.f, 0.f);
        if (m0 + r < M) v = ((const float4*)omean_g)[(size_t)(m0 + r) * 32 + c4];
        *(float4*)&As[r * 132 + c4 * 4] = v;
    }

    const int tn = tid & 31;
    const int tm = tid >> 5;
    float acc[8][4];
#pragma unroll
    for (int m = 0; m < 8; m++)
#pragma unroll
        for (int j = 0; j < 4; j++) acc[m][j] = 0.f;

    for (int ks = 0; ks < 4; ks++) {
        __syncthreads();
#pragma unroll
        for (int i = 0; i < 4; i++) {
            int id = tid + i * 256;          // 1024 = 128 n x 8 q
            int n = id >> 3, q = id & 7;
            float4 w = ((const float4*)Wop)[(size_t)n * 32 + ks * 8 + q];
            *(float4*)&Bs[n * 36 + q * 4] = w;
        }
        __syncthreads();

        for (int k4 = 0; k4 < 8; k4++) {
            float4 a[8];
#pragma unroll
            for (int m = 0; m < 8; m++)
                a[m] = *(const float4*)&As[(tm * 8 + m) * 132 + ks * 32 + k4 * 4];
            float4 b[4];
#pragma unroll
            for (int j = 0; j < 4; j++)
                b[j] = *(const float4*)&Bs[(tn + 32 * j) * 36 + k4 * 4];
#pragma unroll
            for (int m = 0; m < 8; m++) {
                float4 av = a[m];
#pragma unroll
                for (int j = 0; j < 4; j++) {
                    float4 bv = b[j];
                    acc[m][j] += av.x * bv.x + av.y * bv.y
                               + av.z * bv.z + av.w * bv.w;
                }
            }
        }
    }

#pragma unroll
    for (int m = 0; m < 8; m++) {
        int row = m0 + tm * 8 + m;
        if (row < M) {
#pragma unroll
            for (int j = 0; j < 4; j++) {
                int col = tn + 32 * j;
                float* o = &out[(size_t)row * C + col];
                *o += acc[m][j] + bopS[col];
            }
        }
    }
}

// ---------------------------------------------------------------------------
extern "C" void kernel_launch(void* const* d_in, const int* in_sizes, int n_in,
                              void* d_out, int out_size, void* d_ws, size_t ws_size,
                              hipStream_t stream) {
    const float* x_user = (const float*)d_in[0];
    const float* x_item = (const float*)d_in[1];
    const int*   ei_u2i = (const int*)d_in[2];
    const int*   ei_i2u = (const int*)d_in[3];
    const float* W_nb   = (const float*)d_in[4];
    const float* b_nb   = (const float*)d_in[5];
    const float* W_self = (const float*)d_in[6];
    const float* b_self = (const float*)d_in[7];
    const float* Wip    = (const float*)d_in[8];
    const float* bip    = (const float*)d_in[9];
    const float* Wop    = (const float*)d_in[10];
    const float* bop    = (const float*)d_in[11];

    const int NU = in_sizes[0] / C;
    const int NI = in_sizes[1] / C;
    const int E1 = in_sizes[2] / 2;
    const int E2 = in_sizes[3] / 2;
    const int NTOT = NU + NI;

    float* out_user = (float*)d_out;
    float* out_item = out_user + (size_t)NU * C;

    // workspace: wipbf (24576 floats) | h (rc) | omean (rc)
    //          | curA (NI ints) | curB (NU ints) | csrA16 (E1) | csrB16 (E2)
    float* ws = (float*)d_ws;
    short* wipbf     = (short*)ws;
    float* h_all     = ws + 24576;
    const size_t rc = (size_t)NTOT * C;
    float* omean_all = h_all + rc;
    int*   curA      = (int*)(omean_all + rc);     // item-side degrees (NI)
    int*   curB      = curA + NI;                  // user-side degrees (NU)
    unsigned short* csrA16 = (unsigned short*)(curB + NU);
    unsigned short* csrB16 = csrA16 + E1;

    float* h_user = h_all;
    float* h_item = h_all + (size_t)NU * C;
    float* om_user = omean_all;
    float* om_item = omean_all + (size_t)NU * C;

    // K1: transform + prep (wip2bf + zero cur arrays)
    const int TB = (NTOT + 63) / 64;
    const int PB = 96 + (NTOT + 255) / 256;
    transform_prep_kernel<<<TB + PB, 256, 0, stream>>>(
        x_user, x_item, NU, NTOT, W_nb, b_nb, W_self, b_self,
        h_all, (float*)d_out, Wip, (unsigned*)wipbf, curA, NI, curB, NU, TB);

    // K2: merged histogram
    hist2_kernel<<<(E1 + E2 + 255) / 256, 256, 0, stream>>>(
        ei_u2i + E1, E1, curA, ei_i2u + E2, E2, curB);

    // K3: both scans in one launch
    scan2_kernel<<<2, 1024, 0, stream>>>(curA, NI, curB, NU);

    // K4: merged fill (ushort CSR)
    fill2_kernel<<<(E1 + E2 + 255) / 256, 256, 0, stream>>>(
        ei_u2i, ei_u2i + E1, E1, curA, csrA16,
        ei_i2u, ei_i2u + E2, E2, curB, csrB16);

    // K5a: direction B (item -> user)
    attn_fused_kernel<<<(NU + ATN - 1) / ATN, 256, 0, stream>>>(
        h_item, csrB16, curB, out_user, wipbf, bip, om_user, NU);

    // K5b: direction A (user -> item)
    attn_fused_kernel<<<(NI + ATN - 1) / ATN, 256, 0, stream>>>(
        h_user, csrA16, curA, out_item, wipbf, bip, om_item, NI);

    // K6: output projection
    outproj_kernel<<<(NTOT + 63) / 64, 256, 0, stream>>>(
        omean_all, Wop, bop, (float*)d_out, NTOT);
}